// Round 1
// baseline (230.565 us; speedup 1.0000x reference)
//
#include <hip/hip_runtime.h>
#include <float.h>
#include <math.h>

#define K_CODES 1024
#define ED 64
#define NTOK 131072
#define EPS 4e-4f   // flag band; approx-vs-exact bound ~7e-5 -> 6x margin

typedef __attribute__((ext_vector_type(8)))  short short8;   // 8 bf16 (4 VGPRs)
typedef __attribute__((ext_vector_type(16))) float float16;  // MFMA 32x32 acc

// ---------------------------------------------------------------------------
// NUMERICS OF THE EXACT PATH ARE FROZEN (rounds 2/4/5/6 passed, 0 flips):
//  - zsq / e_sq: numpy pairwise_sum n=64 (8 accs strided 8, mul+add no fma,
//    combine ((r0+r1)+(r2+r3))+((r4+r5)+(r6+r7))), contract(off).
//  - dot(z,e): single sequential fmaf chain over d=0..63.
//  - d2 = fmaf(-2,dot,zsq) + e_sq.
//  - argmin: first index wins (lexicographic (value,index) updates).
// Phase 1 (MFMA bf16 hi/lo) only selects candidates; tokens with a single
// in-band candidate and no in-band rival take it WITHOUT rescoring (band
// proof: all other codes are > EPS - 2*approx_err - esq_spread away).
// Exact ties inside a tile force tB==tA -> fullmask -> full 32-scan.
//
// Round-7 change (this file): vq_exact only. The previous version kept
// runtime-indexed cand[8] (rule #20 -> scratch) and an eb[64] staging array;
// VGPR_Count=52 proved the hot arrays were NOT register-resident, putting
// private-segment (scratch) latency on every thread's critical chain ->
// all-pipes-idle signature (VALU 8%, HBM 11%, 76us). Now: bitmask candidate
// tracking (no runtime-indexed arrays), frozen fmaf chain consumes gathered
// float4 directly (no eb[]), launch_bounds(256,2) = 256-VGPR budget matched
// to the 8-waves/CU grid ceiling. Candidate SET is a superset containing all
// exact-min achievers and comparison is a total order on (d2, idx), so bi is
// unchanged token-for-token.
// ---------------------------------------------------------------------------

static __device__ __forceinline__ unsigned short f2bf(float x) {  // RNE
    unsigned u = __float_as_uint(x);
    u += 0x7fffu + ((u >> 16) & 1u);
    return (unsigned short)(u >> 16);
}
static __device__ __forceinline__ float bf2f(unsigned short h) {
    return __uint_as_float(((unsigned)h) << 16);
}

// ---------------------------------------------------------------------------
// pre: blocks 0..511 tokens (zsq + z bf16-split fragments);
//      blocks 512..515 codes (e_sq + e bf16-split frags, zero counts/sse).
// frag[(row32tile*8 + g)*32 + (row&31)], g = d/8, lane k-half h = g&1.
// ---------------------------------------------------------------------------
__global__ __launch_bounds__(256) void vq_pre(const float* __restrict__ z_e,
                                              const float* __restrict__ cb,
                                              float* __restrict__ zsq_g,
                                              short8* __restrict__ zfH,
                                              short8* __restrict__ zfL,
                                              float* __restrict__ e_sq,
                                              short8* __restrict__ efH,
                                              short8* __restrict__ efL,
                                              unsigned int* __restrict__ counts,
                                              float* __restrict__ sse)
{
#pragma clang fp contract(off)
    const int tid = threadIdx.x;
    if (blockIdx.x < NTOK / 256) {
        const int t = blockIdx.x * 256 + tid;
        const float4* zp = (const float4*)(z_e + (size_t)t * ED);
        const int n = t & 31, tt = t >> 5;
        float r[8];
#pragma unroll
        for (int g = 0; g < 8; ++g) {
            float4 a = zp[2 * g], b = zp[2 * g + 1];
            float v[8] = {a.x, a.y, a.z, a.w, b.x, b.y, b.z, b.w};
            short8 hv, lv;
#pragma unroll
            for (int j = 0; j < 8; ++j) {
                unsigned short hb = f2bf(v[j]);
                hv[j] = (short)hb;
                lv[j] = (short)f2bf(v[j] - bf2f(hb));
                const float sq = v[j] * v[j];          // frozen pairwise zsq
                r[j] = g ? (r[j] + sq) : sq;
            }
            zfH[(tt * 8 + g) * 32 + n] = hv;
            zfL[(tt * 8 + g) * 32 + n] = lv;
        }
        zsq_g[t] = ((r[0] + r[1]) + (r[2] + r[3])) + ((r[4] + r[5]) + (r[6] + r[7]));
    } else {
        const int k = (blockIdx.x - NTOK / 256) * 256 + tid;   // 0..1023
        const float4* ep = (const float4*)(cb + (size_t)k * ED);
        const int m = k & 31, ct = k >> 5;
        float r[8];
#pragma unroll
        for (int g = 0; g < 8; ++g) {
            float4 a = ep[2 * g], b = ep[2 * g + 1];
            float v[8] = {a.x, a.y, a.z, a.w, b.x, b.y, b.z, b.w};
            short8 hv, lv;
#pragma unroll
            for (int j = 0; j < 8; ++j) {
                unsigned short hb = f2bf(v[j]);
                hv[j] = (short)hb;
                lv[j] = (short)f2bf(v[j] - bf2f(hb));
                const float sq = v[j] * v[j];          // frozen pairwise e_sq
                r[j] = g ? (r[j] + sq) : sq;
            }
            efH[(ct * 8 + g) * 32 + m] = hv;
            efL[(ct * 8 + g) * 32 + m] = lv;
        }
        e_sq[k] = ((r[0] + r[1]) + (r[2] + r[3])) + ((r[4] + r[5]) + (r[6] + r[7]));
        counts[k] = 0u;
        if (k == 0) *sse = 0.f;
    }
}

// ---------------------------------------------------------------------------
// phase 1: approx scores via bf16 MFMA (hh, h*l, l*h).
// Wave owns 64 codes (2 m-tiles, A-frags in regs); blockIdx.y = code group.
// Store per (token, 32-code tile): tA = -2*maxdot (low 5 mantissa bits =
// in-tile argmax row), tB = -2*secondmax.
// ---------------------------------------------------------------------------
__global__ __launch_bounds__(256, 2) void vq_approx(const short8* __restrict__ zfH,
                                                    const short8* __restrict__ zfL,
                                                    const short8* __restrict__ efH,
                                                    const short8* __restrict__ efL,
                                                    float* __restrict__ tA,
                                                    float* __restrict__ tB)
{
    const int tid = threadIdx.x;
    const int lane = tid & 63, wv = tid >> 6;
    const int h = lane >> 5, ml = lane & 31;
    const int ct0 = blockIdx.y * 8 + wv * 2;       // wave's two 32-code tiles

    short8 ea[2][4], eb[2][4];                     // A-frags: eh, el (in regs)
#pragma unroll
    for (int mt = 0; mt < 2; ++mt) {
        const int ct = ct0 + mt;
#pragma unroll
        for (int q = 0; q < 4; ++q) {
            const int idx = (ct * 8 + q * 2 + h) * 32 + ml;
            ea[mt][q] = efH[idx];
            eb[mt][q] = efL[idx];
        }
    }

    const int tt0 = blockIdx.x * 8;
    for (int it = 0; it < 8; ++it) {
        const int tt = tt0 + it;
        short8 zh[4], zl[4];
#pragma unroll
        for (int q = 0; q < 4; ++q) {
            const int idx = (tt * 8 + q * 2 + h) * 32 + ml;
            zh[q] = zfH[idx];
            zl[q] = zfL[idx];
        }
        float16 acc0 = {}, acc1 = {};
#pragma unroll
        for (int q = 0; q < 4; ++q) {
            acc0 = __builtin_amdgcn_mfma_f32_32x32x16_bf16(ea[0][q], zh[q], acc0, 0, 0, 0);
            acc1 = __builtin_amdgcn_mfma_f32_32x32x16_bf16(ea[1][q], zh[q], acc1, 0, 0, 0);
            acc0 = __builtin_amdgcn_mfma_f32_32x32x16_bf16(ea[0][q], zl[q], acc0, 0, 0, 0);
            acc1 = __builtin_amdgcn_mfma_f32_32x32x16_bf16(ea[1][q], zl[q], acc1, 0, 0, 0);
            acc0 = __builtin_amdgcn_mfma_f32_32x32x16_bf16(eb[0][q], zh[q], acc0, 0, 0, 0);
            acc1 = __builtin_amdgcn_mfma_f32_32x32x16_bf16(eb[1][q], zh[q], acc1, 0, 0, 0);
        }
#pragma unroll
        for (int mt = 0; mt < 2; ++mt) {
            const float16 acc = mt ? acc1 : acc0;
            float v1 = -FLT_MAX, v2 = -FLT_MAX;
            int i1 = 0;
#pragma unroll
            for (int rg = 0; rg < 16; ++rg) {
                const float v = acc[rg];
                const int mrow = (rg & 3) + 8 * (rg >> 2) + 4 * h;  // C/D row (m74/m101)
                if (v > v1) { v2 = v1; v1 = v; i1 = mrow; }
                else v2 = fmaxf(v2, v);
            }
            const float o1 = __shfl_xor(v1, 32);
            const float o2 = __shfl_xor(v2, 32);
            const int   oi = __shfl_xor(i1, 32);
            const float lo = fminf(v1, o1);
            if (o1 > v1) { v1 = o1; i1 = oi; }
            v2 = fmaxf(lo, fmaxf(v2, o2));          // exact 2nd-largest merge
            if (lane < 32) {
                const int t = tt * 32 + lane;        // C/D col = token
                const unsigned bits = (__float_as_uint(-2.f * v1) & ~31u) | (unsigned)i1;
                tA[(size_t)(ct0 + mt) * NTOK + t] = __uint_as_float(bits);
                tB[(size_t)(ct0 + mt) * NTOK + t] = -2.f * v2;
            }
        }
    }
}

// ---------------------------------------------------------------------------
// phase 2: candidate selection; exact rescore (frozen chain) ONLY for
// ambiguous tokens (~1-2%); fused epilogue. Divergent per-thread loops so
// masked lanes issue no gather traffic. Round-7: no runtime-indexed private
// arrays (bandmask/fullmask bitmasks + cand0 scalar), no eb[] staging (the
// frozen fmaf chain consumes gathered float4 directly, same d=0..63 order),
// launch_bounds(256,2) so av[32]+zr[64] stay in VGPRs.
// ---------------------------------------------------------------------------

// Frozen exact rescore of code (cc): single sequential fmaf chain d=0..63,
// d2 = fmaf(-2,dot,zsq) + e_sq; lexicographic (d2, idx) update. Macro (not a
// function) so the caller's fp-contract(off) region and register allocation
// apply directly; all zr indices are compile-time constants after unroll.
#define RESCORE(cc)                                                          \
    do {                                                                     \
        const int c_ = (cc);                                                 \
        const float4* e4_ = (const float4*)(cb + (size_t)c_ * ED);           \
        float a_ = 0.f;                                                      \
        _Pragma("unroll")                                                    \
        for (int jj_ = 0; jj_ < 16; ++jj_) {                                 \
            const float4 v_ = e4_[jj_];                                      \
            a_ = fmaf(zr[4 * jj_ + 0], v_.x, a_);                            \
            a_ = fmaf(zr[4 * jj_ + 1], v_.y, a_);                            \
            a_ = fmaf(zr[4 * jj_ + 2], v_.z, a_);                            \
            a_ = fmaf(zr[4 * jj_ + 3], v_.w, a_);                            \
        }                                                                    \
        const float d2_ = fmaf(-2.f, a_, zsq) + e_sq[c_];                    \
        if (d2_ < best || (d2_ == best && c_ < bi)) { best = d2_; bi = c_; } \
    } while (0)

__global__ __launch_bounds__(256, 2) void vq_exact(const float* __restrict__ z_e,
                                                   const float* __restrict__ cb,
                                                   const float* __restrict__ e_sq,
                                                   const float* __restrict__ zsq_g,
                                                   const float* __restrict__ tA,
                                                   const float* __restrict__ tB,
                                                   float* __restrict__ out_zq,
                                                   float* __restrict__ out_idx,
                                                   unsigned int* __restrict__ counts,
                                                   float* __restrict__ sse)
{
#pragma clang fp contract(off)
    __shared__ unsigned int hist[K_CODES];
    __shared__ float wsum[4];
    const int tid = threadIdx.x;
    for (int i = tid; i < K_CODES; i += 256) hist[i] = 0u;
    __syncthreads();

    const int t = blockIdx.x * 256 + tid;

    // z into regs first: independent of the tA scan, overlaps its latency.
    // Needed for SSE regardless of path. Static indices only -> VGPRs.
    const float4* zp = (const float4*)(z_e + (size_t)t * ED);
    float zr[ED];
#pragma unroll
    for (int i = 0; i < 16; ++i) {
        const float4 v = zp[i];
        zr[4 * i + 0] = v.x; zr[4 * i + 1] = v.y;
        zr[4 * i + 2] = v.z; zr[4 * i + 3] = v.w;
    }

    // single pass over tA: buffer in regs (static idx), min
    float av[32];
    float m = FLT_MAX;
#pragma unroll
    for (int ct = 0; ct < 32; ++ct) {
        av[ct] = tA[(size_t)ct * NTOK + t];
        m = fminf(m, av[ct]);
    }
    const float thr = m + EPS;

    // Band scan: bitmask of in-band tiles; fullmask where the tile's
    // second-best is also in band (same tB<=thr test as before). cand0 is
    // the first in-band tile's candidate, recorded under a STATIC index.
    unsigned bandmask = 0u, fullmask = 0u;
    int cand0 = 0, nband = 0;
#pragma unroll
    for (int ct = 0; ct < 32; ++ct) {
        if (av[ct] <= thr) {
            if (nband == 0)
                cand0 = ct * 32 + (int)(__float_as_uint(av[ct]) & 31u);
            ++nband;
            bandmask |= (1u << ct);
            if (tB[(size_t)ct * NTOK + t] <= thr) fullmask |= (1u << ct);
        }
    }

    int bi;
    if (nband == 1 && fullmask == 0u) {
        bi = cand0;                     // unambiguous: band proves exact argmin
    } else {
        // Rare path (~1-2% of lanes). Rescore every in-band tile's candidate
        // (re-derived from an L3-hot tA reload -> no runtime-indexed array),
        // and the full 32 codes of tB-flagged tiles. This set is a superset
        // of the previous cand[8]+overflow scheme and contains all exact-min
        // achievers; (d2, idx) is a total order, so bi is identical.
        const float zsq = zsq_g[t];
        float best = FLT_MAX;
        bi = 0;
        unsigned rem = bandmask;
        while (rem) {
            const int ct = __ffs(rem) - 1;
            rem &= rem - 1;
            if (fullmask & (1u << ct)) {
                for (int j = 0; j < 32; ++j) RESCORE(ct * 32 + j);
            } else {
                const int c = ct * 32 +
                    (int)(__float_as_uint(tA[(size_t)ct * NTOK + t]) & 31u);
                RESCORE(c);
            }
        }
    }

    atomicAdd(&hist[bi], 1u);
    out_idx[t] = (float)bi;

    // gather selected code, write z_q, SSE (frozen fmaf chain, d order)
    const float4* eq = (const float4*)(cb + (size_t)bi * ED);
    float4* oz = (float4*)(out_zq + (size_t)t * ED);
    float lsse = 0.f;
#pragma unroll
    for (int i = 0; i < 16; ++i) {
        float4 q = eq[i];
        oz[i] = q;
        float dx = q.x - zr[4 * i + 0]; lsse = fmaf(dx, dx, lsse);
        float dy = q.y - zr[4 * i + 1]; lsse = fmaf(dy, dy, lsse);
        float dz = q.z - zr[4 * i + 2]; lsse = fmaf(dz, dz, lsse);
        float dw = q.w - zr[4 * i + 3]; lsse = fmaf(dw, dw, lsse);
    }
#pragma unroll
    for (int off = 32; off > 0; off >>= 1)
        lsse += __shfl_down(lsse, off, 64);
    const int lane = tid & 63, wid = tid >> 6;
    if (lane == 0) wsum[wid] = lsse;
    __syncthreads();
    if (tid == 0)
        atomicAdd(sse, (wsum[0] + wsum[1]) + (wsum[2] + wsum[3]));
    for (int i = tid; i < K_CODES; i += 256) {
        const unsigned int c = hist[i];
        if (c) atomicAdd(&counts[i], c);
    }
}

// ---------------------------------------------------------------------------
// final: entropy / losses scalars
// ---------------------------------------------------------------------------
__global__ __launch_bounds__(1024) void vq_final(const unsigned int* __restrict__ counts,
                                                 const float* __restrict__ sse,
                                                 float* __restrict__ out_sc)
{
    __shared__ float red[1024];
    const int i = threadIdx.x;
    const float c = (float)counts[i];
    const float p = c / (float)NTOK + 1e-10f;
    red[i] = p * logf(p);
    __syncthreads();
    for (int s = 512; s > 0; s >>= 1) {
        if (i < s) red[i] += red[i + s];
        __syncthreads();
    }
    if (i == 0) {
        const float entropy = -red[0];
        const float cbl = (*sse) / ((float)NTOK * (float)ED);
        out_sc[0] = cbl;                                   // codebook_loss
        out_sc[1] = 0.25f * cbl;                           // commitment_loss
        out_sc[2] = -0.1f * (entropy / 6.93147180559945f); // entropy_loss
        out_sc[3] = expf(entropy);                         // perplexity
    }
}

// ---------------------------------------------------------------------------
extern "C" void kernel_launch(void* const* d_in, const int* in_sizes, int n_in,
                              void* d_out, int out_size, void* d_ws, size_t ws_size,
                              hipStream_t stream)
{
    const float* z_e = (const float*)d_in[0];
    const float* cb  = (const float*)d_in[1];

    float* out   = (float*)d_out;
    float* o_zq  = out;                              // [131072,64]
    float* o_idx = out + (size_t)NTOK * ED;          // [131072] (as float)
    float* o_sc  = o_idx + NTOK;                     // 4 scalars

    char* ws = (char*)d_ws;
    float*        e_sq   = (float*)(ws);                     // 4 KB
    unsigned int* counts = (unsigned int*)(ws + 4096);       // 4 KB
    float*        sse    = (float*)(ws + 8192);              // 4 B
    float*        zsq_g  = (float*)(ws + 8448);              // 512 KB
    short8*       efH    = (short8*)(ws + 532736);           // 128 KB
    short8*       efL    = (short8*)(ws + 663808);           // 128 KB
    short8*       zfH    = (short8*)(ws + (1u << 20));       // 16 MB
    short8*       zfL    = (short8*)(ws + 17825792);         // 16 MB
    float*        tA     = (float*)(ws + 34603008);          // 16 MB
    float*        tB     = (float*)(ws + 51380224);          // 16 MB (end 64 MB)

    vq_pre   <<<NTOK / 256 + 4, 256, 0, stream>>>(z_e, cb, zsq_g, zfH, zfL,
                                                  e_sq, efH, efL, counts, sse);
    vq_approx<<<dim3(NTOK / 256, 4), 256, 0, stream>>>(zfH, zfL, efH, efL, tA, tB);
    vq_exact <<<NTOK / 256, 256, 0, stream>>>(z_e, cb, e_sq, zsq_g, tA, tB,
                                              o_zq, o_idx, counts, sse);
    vq_final <<<1, 1024, 0, stream>>>(counts, sse, o_sc);
}